// Round 6
// baseline (661.966 us; speedup 1.0000x reference)
//
#include <hip/hip_runtime.h>
#include <cmath>

// ============================================================================
// AutoregressiveGroupQuerySelfAttention  (B=2, S=2048, H=2048, nH=16, D=128)
//
// Round 6:
//  - attn: LDS-read-throughput bound (model: 50 b128/wave-iter x 12cyc
//    matches measured 201us within 8%). Fix: wave owns 32 q-rows (2 m-frags),
//    256-thread blocks, so every K/V B-fragment read feeds 2 MFMAs.
//    Per-block-iter LDS ops 6.2k -> 3.9k cyc. Grid stays 512 = 2 blocks/CU
//    (complementary qt pairing). launch_bounds(256,2): 256-VGPR cap, no
//    spill (R4 lesson: tighter caps spill ~300MB scratch).
//  - Everything else unchanged from R5 (attribution).
// ============================================================================

typedef unsigned short u16;
typedef __attribute__((ext_vector_type(4))) float  f32x4;
typedef __attribute__((ext_vector_type(4))) float  float4v;
typedef __attribute__((ext_vector_type(4))) unsigned short u16x4;
typedef __attribute__((ext_vector_type(8))) unsigned short u16x8;
typedef __attribute__((ext_vector_type(8))) short s16x8;

__device__ __forceinline__ u16 f2bf(float f) {
  unsigned u = __float_as_uint(f);
  u += 0x7FFFu + ((u >> 16) & 1u);            // RNE; inputs are finite
  return (u16)(u >> 16);
}
__device__ __forceinline__ float bf2f(u16 h) {
  return __uint_as_float(((unsigned)h) << 16);
}
__device__ __forceinline__ f32x4 MFMA(s16x8 a, s16x8 b, f32x4 c) {
  return __builtin_amdgcn_mfma_f32_16x16x32_bf16(a, b, c, 0, 0, 0);
}
// async global->LDS, 16B per lane; LDS dest = wave-uniform base + lane*16
__device__ __forceinline__ void gld16(const void* g, void* s) {
  __builtin_amdgcn_global_load_lds(
      (const __attribute__((address_space(1))) void*)g,
      (__attribute__((address_space(3))) void*)s, 16, 0, 0);
}

// ---------------------------------------------------------------------------
// fp32 -> bf16 hi (+ optional lo residual).  n4 = element count / 4.
// ---------------------------------------------------------------------------
__global__ void split_bf16(const float* __restrict__ src, u16* __restrict__ hi,
                           u16* __restrict__ lo, int n4) {
  int i = blockIdx.x * 256 + threadIdx.x;
  if (i >= n4) return;
  float4v v = ((const float4v*)src)[i];
  u16x4 hv, lv;
#pragma unroll
  for (int j = 0; j < 4; ++j) {
    float f = v[j];
    u16 h = f2bf(f);
    hv[j] = h;
    lv[j] = f2bf(f - bf2f(h));
  }
  ((u16x4*)hi)[i] = hv;
  if (lo) ((u16x4*)lo)[i] = lv;
}

// ---------------------------------------------------------------------------
// RoPE tables in fp64.
// ---------------------------------------------------------------------------
__global__ void rope_tab(float* __restrict__ cosT, float* __restrict__ sinT) {
  int idx = blockIdx.x * 256 + threadIdx.x;   // 2048*64
  int i = idx & 63, s = idx >> 6;
  double invf = pow(10000.0, -(double)i / 64.0);
  double ang = (double)s * invf;
  cosT[idx] = (float)cos(ang);
  sinT[idx] = (float)sin(ang);
}

// ---------------------------------------------------------------------------
// GEMM  C(MxN) = A(MxK) * B(NxK)^T, bf16 inputs, fp32 accumulate.
// NTERM==3: split precision (hh+hl+lh).
// OMODE: 0 fp32, 1 bf16 hi/lo, 2 bf16.   ROPE: fuse rotation in epilogue.
// 128x128 tile, BK=32, 4 waves each 32(m) x 128(n): acc[2][8].
// Staging via global_load_lds (16B/lane), unpadded LDS [128][32].
// ---------------------------------------------------------------------------
template <int NTERM, int OMODE, int ROPE>
__global__ __launch_bounds__(256, 3)
void gemm_bt(const u16* __restrict__ Ah, const u16* __restrict__ Al,
             const u16* __restrict__ Bh, const u16* __restrict__ Bl,
             float* __restrict__ Cf, u16* __restrict__ Ch, u16* __restrict__ Cl,
             const float* __restrict__ cosT, const float* __restrict__ sinT,
             float scale, int M, int N, int K) {
  __shared__ u16 As[128 * 32];
  __shared__ u16 Bs[128 * 32];
  __shared__ u16 Asl[NTERM == 3 ? 128 * 32 : 8];
  __shared__ u16 Bsl[NTERM == 3 ? 128 * 32 : 8];
  const int bn = blockIdx.x, bm = blockIdx.y;
  const int t = threadIdx.x;
  const int w = t >> 6, lane = t & 63, quad = lane >> 4, lc = lane & 15;

  const f32x4 ZERO = {0.f, 0.f, 0.f, 0.f};
  f32x4 acc[2][8];
#pragma unroll
  for (int i = 0; i < 2; ++i)
#pragma unroll
    for (int j = 0; j < 8; ++j) acc[i][j] = ZERO;

  const int sr0 = (lane >> 2);
  const int sc0 = (lane & 3) * 8;
  const size_t arow0 = (size_t)bm * 128, brow0 = (size_t)bn * 128;

  for (int k0 = 0; k0 < K; k0 += 32) {
#pragma unroll
    for (int p = 0; p < 2; ++p) {
      const int ch = 2 * w + p;
      const int r = ch * 16 + sr0;
      const size_t ga = (arow0 + r) * (size_t)K + k0 + sc0;
      const size_t gb = (brow0 + r) * (size_t)K + k0 + sc0;
      const int ldso = ch * 512 + lane * 8;   // u16 index
      gld16(&Ah[ga], &As[ldso]);
      gld16(&Bh[gb], &Bs[ldso]);
      if constexpr (NTERM == 3) {
        gld16(&Al[ga], &Asl[ldso]);
        gld16(&Bl[gb], &Bsl[ldso]);
      }
    }
    __syncthreads();

    s16x8 ah[2], al[2];
#pragma unroll
    for (int i = 0; i < 2; ++i) {
      ah[i] = *(const s16x8*)&As[(32 * w + 16 * i + lc) * 32 + 8 * quad];
      if constexpr (NTERM == 3)
        al[i] = *(const s16x8*)&Asl[(32 * w + 16 * i + lc) * 32 + 8 * quad];
    }
#pragma unroll
    for (int j = 0; j < 8; ++j) {
      const s16x8 bh = *(const s16x8*)&Bs[(16 * j + lc) * 32 + 8 * quad];
      s16x8 bl;
      if constexpr (NTERM == 3)
        bl = *(const s16x8*)&Bsl[(16 * j + lc) * 32 + 8 * quad];
#pragma unroll
      for (int i = 0; i < 2; ++i) {
        acc[i][j] = MFMA(ah[i], bh, acc[i][j]);
        if constexpr (NTERM == 3) {
          acc[i][j] = MFMA(ah[i], bl, acc[i][j]);
          acc[i][j] = MFMA(al[i], bh, acc[i][j]);
        }
      }
    }
    __syncthreads();
  }

  // ---- epilogue ----
  if constexpr (ROPE) {
    // N-tile 128 == one head (bn*128 head-aligned). Pair cols d and d+64.
#pragma unroll
    for (int i = 0; i < 2; ++i)
#pragma unroll
      for (int r = 0; r < 4; ++r) {
        const int row = bm * 128 + 32 * w + 16 * i + 4 * quad + r;
        const int s = row & 2047;
#pragma unroll
        for (int j = 0; j < 4; ++j) {
          const int hd = 16 * j + lc;
          const float cs = cosT[s * 64 + hd], sn = sinT[s * 64 + hd];
          const float q1 = acc[i][j][r], q2 = acc[i][j + 4][r];
          const float o1 = (q1 * cs - q2 * sn) * scale;
          const float o2 = (q2 * cs + q1 * sn) * scale;
          const size_t p1 = (size_t)row * N + bn * 128 + hd;
          const u16 h1 = f2bf(o1);
          Ch[p1] = h1; Cl[p1] = f2bf(o1 - bf2f(h1));
          const u16 h2 = f2bf(o2);
          Ch[p1 + 64] = h2; Cl[p1 + 64] = f2bf(o2 - bf2f(h2));
        }
      }
  } else {
#pragma unroll
    for (int i = 0; i < 2; ++i)
#pragma unroll
      for (int j = 0; j < 8; ++j) {
        const int col = bn * 128 + 16 * j + lc;
#pragma unroll
        for (int r = 0; r < 4; ++r) {
          const int row = bm * 128 + 32 * w + 16 * i + 4 * quad + r;
          const float v = acc[i][j][r];
          if constexpr (OMODE == 0) {
            Cf[(size_t)row * N + col] = v;
          } else if constexpr (OMODE == 1) {
            const u16 hv = f2bf(v);
            Ch[(size_t)row * N + col] = hv;
            Cl[(size_t)row * N + col] = f2bf(v - bf2f(hv));
          } else {
            Ch[(size_t)row * N + col] = f2bf(v);
          }
        }
      }
  }
}

// ---------------------------------------------------------------------------
// Flash attention, causal. Q pre-scaled by sqrt(D) (folded into GEMM epilogue).
// grid (16 x, 16 heads, 2 batches), qt = z ? x : 15-x (complementary pairing).
// 256 threads = 4 waves; wave w owns q-rows 32w..32w+31 (2 m-frags) so each
// K/V B-fragment LDS read feeds 2 MFMAs (halves LDS read traffic per work).
// kN=64, single LDS buffer (71.7 KB -> 2 blocks/CU), VGPR prefetch of kt+1.
// V^T layout: Vt[dim=h*128+d][b*2048+s], row stride 4096.
// ---------------------------------------------------------------------------
__global__ __launch_bounds__(256, 2)
void attn(const u16* __restrict__ Qh, const u16* __restrict__ Ql,
          const u16* __restrict__ Kh, const u16* __restrict__ Kl,
          const u16* __restrict__ Vt, u16* __restrict__ Ctx) {
  constexpr int LDK = 136;   // 64 k-rows x 128 d (+8 pad)
  constexpr int LDV = 72;    // 128 d-rows x 64 s (+8 pad)
  constexpr int LDP = 72;    // 128 q-rows x 64 k (+8 pad)
  __shared__ u16 Ksh[64 * LDK];
  __shared__ u16 Ksl[64 * LDK];
  __shared__ u16 Vts[128 * LDV];
  __shared__ u16 Ps[128 * LDP];

  const int qt = blockIdx.z ? (int)blockIdx.x : 15 - (int)blockIdx.x;
  const int h = blockIdx.y, b = blockIdx.z;
  const int t = threadIdx.x;
  const int w = t >> 6, lane = t & 63, quad = lane >> 4, lc = lane & 15;

  // Q fragments in registers (A-layout: A[m=lane&15][k=quad*8+j]).
  s16x8 qfh[2][4], qfl[2][4];
#pragma unroll
  for (int mt = 0; mt < 2; ++mt)
#pragma unroll
    for (int s = 0; s < 4; ++s) {
      const size_t g = ((size_t)(b * 2048 + qt * 128 + 32 * w + 16 * mt + lc)) * 2048
                       + h * 128 + 32 * s + 8 * quad;
      qfh[mt][s] = *(const s16x8*)&Qh[g];
      qfl[mt][s] = *(const s16x8*)&Ql[g];
    }

  const f32x4 ZERO = {0.f, 0.f, 0.f, 0.f};
  float m_run[2][4], l_run[2][4];
  f32x4 o[2][8];
#pragma unroll
  for (int mt = 0; mt < 2; ++mt) {
#pragma unroll
    for (int r = 0; r < 4; ++r) { m_run[mt][r] = -3.0e38f; l_run[mt][r] = 0.f; }
#pragma unroll
    for (int dt = 0; dt < 8; ++dt) o[mt][dt] = ZERO;
  }

  const u16* gKh0 = Kh + ((size_t)(b * 2048)) * 2048 + h * 128;
  const u16* gKl0 = Kl + ((size_t)(b * 2048)) * 2048 + h * 128;
  const u16* gV0  = Vt + (size_t)(h * 128) * 4096 + b * 2048;   // row stride 4096

  const int ktmax = 2 * qt + 1;
  // staging maps (256 threads):
  //   K tile 64x128: row (t>>4)+16p, col (t&15)*8,  p=0..3
  //   V tile 128x64: row (t>>3)+32p, col (t&7)*8,   p=0..3
  const int kr0 = t >> 4, kc0 = (t & 15) * 8;
  const int vr0 = t >> 3, vc0 = (t & 7) * 8;

  u16x8 pKh[4], pKl[4], pV[4];

  // ---- prefetch tile 0 into VGPRs ----
#pragma unroll
  for (int p = 0; p < 4; ++p) {
    pKh[p] = *(const u16x8*)&gKh0[(size_t)(kr0 + 16 * p) * 2048 + kc0];
    pKl[p] = *(const u16x8*)&gKl0[(size_t)(kr0 + 16 * p) * 2048 + kc0];
    pV[p]  = *(const u16x8*)&gV0[(size_t)(vr0 + 32 * p) * 4096 + vc0];
  }

  for (int kt = 0; kt <= ktmax; ++kt) {
    // ---- commit prefetched tile to LDS ----
#pragma unroll
    for (int p = 0; p < 4; ++p) {
      *(u16x8*)&Ksh[(kr0 + 16 * p) * LDK + kc0] = pKh[p];
      *(u16x8*)&Ksl[(kr0 + 16 * p) * LDK + kc0] = pKl[p];
      *(u16x8*)&Vts[(vr0 + 32 * p) * LDV + vc0] = pV[p];
    }
    __syncthreads();

    // ---- prefetch next tile (global latency overlaps compute) ----
    if (kt < ktmax) {
#pragma unroll
      for (int p = 0; p < 4; ++p) {
        pKh[p] = *(const u16x8*)&gKh0[(size_t)((kt + 1) * 64 + kr0 + 16 * p) * 2048 + kc0];
        pKl[p] = *(const u16x8*)&gKl0[(size_t)((kt + 1) * 64 + kr0 + 16 * p) * 2048 + kc0];
        pV[p]  = *(const u16x8*)&gV0[(size_t)(vr0 + 32 * p) * 4096 + (kt + 1) * 64 + vc0];
      }
    }

    // wave fully above the causal frontier at this k-tile?
    const bool active = (qt * 128 + 32 * w + 31) >= kt * 64;
    if (active) {
      // ---- S = Q K^T, split precision; B-frag shared across both m-frags ----
      f32x4 acc[2][4];
#pragma unroll
      for (int mt = 0; mt < 2; ++mt)
#pragma unroll
        for (int c8 = 0; c8 < 4; ++c8) acc[mt][c8] = ZERO;
#pragma unroll
      for (int c8 = 0; c8 < 4; ++c8) {
#pragma unroll
        for (int s = 0; s < 4; ++s) {
          const s16x8 bh = *(const s16x8*)&Ksh[(16 * c8 + lc) * LDK + 32 * s + 8 * quad];
          const s16x8 bl = *(const s16x8*)&Ksl[(16 * c8 + lc) * LDK + 32 * s + 8 * quad];
#pragma unroll
          for (int mt = 0; mt < 2; ++mt) {
            acc[mt][c8] = MFMA(qfh[mt][s], bh, acc[mt][c8]);
            acc[mt][c8] = MFMA(qfh[mt][s], bl, acc[mt][c8]);
            acc[mt][c8] = MFMA(qfl[mt][s], bh, acc[mt][c8]);
          }
        }
      }

      // ---- online softmax per m-frag ----
      const bool diag = (kt >= 2 * qt);
#pragma unroll
      for (int mt = 0; mt < 2; ++mt) {
        float pvv[4][4];
#pragma unroll
        for (int c8 = 0; c8 < 4; ++c8)
#pragma unroll
          for (int r = 0; r < 4; ++r) {
            float v = acc[mt][c8][r];
            if (diag && (kt * 64 + 16 * c8 + lc) >
                        (qt * 128 + 32 * w + 16 * mt + 4 * quad + r))
              v = -3.0e38f;
            pvv[c8][r] = v;
          }
#pragma unroll
        for (int r = 0; r < 4; ++r) {
          float mx = fmaxf(fmaxf(pvv[0][r], pvv[1][r]), fmaxf(pvv[2][r], pvv[3][r]));
          mx = fmaxf(mx, __shfl_xor(mx, 1));
          mx = fmaxf(mx, __shfl_xor(mx, 2));
          mx = fmaxf(mx, __shfl_xor(mx, 4));
          mx = fmaxf(mx, __shfl_xor(mx, 8));
          const float mn = fmaxf(m_run[mt][r], mx);
          const float al = __expf(m_run[mt][r] - mn);
          m_run[mt][r] = mn;
          float rs = 0.f;
#pragma unroll
          for (int c8 = 0; c8 < 4; ++c8) {
            const float e = __expf(pvv[c8][r] - mn);
            pvv[c8][r] = e;
            rs += e;
          }
          rs += __shfl_xor(rs, 1);
          rs += __shfl_xor(rs, 2);
          rs += __shfl_xor(rs, 4);
          rs += __shfl_xor(rs, 8);
          l_run[mt][r] = l_run[mt][r] * al + rs;
#pragma unroll
          for (int dt = 0; dt < 8; ++dt) o[mt][dt][r] *= al;
        }
        // pack P (bf16, unnormalized) -> Ps[qrow][kcol]; own rows only
#pragma unroll
        for (int c8 = 0; c8 < 4; ++c8)
#pragma unroll
          for (int r = 0; r < 4; ++r)
            Ps[(32 * w + 16 * mt + 4 * quad + r) * LDP + 16 * c8 + lc] =
                f2bf(pvv[c8][r]);
      }

      // ---- O += P * V  (B-frag shared across both m-frags) ----
#pragma unroll
      for (int s = 0; s < 2; ++s) {
        s16x8 af[2];
#pragma unroll
        for (int mt = 0; mt < 2; ++mt)
          af[mt] = *(const s16x8*)&Ps[(32 * w + 16 * mt + lc) * LDP + 32 * s + 8 * quad];
#pragma unroll
        for (int dt = 0; dt < 8; ++dt) {
          const s16x8 bv = *(const s16x8*)&Vts[(16 * dt + lc) * LDV + 32 * s + 8 * quad];
#pragma unroll
          for (int mt = 0; mt < 2; ++mt) o[mt][dt] = MFMA(af[mt], bv, o[mt][dt]);
        }
      }
    }
    __syncthreads();   // protect K/V tiles before next commit
  }

  // ---- normalize + store bf16 ctx (B,S,H) ----
#pragma unroll
  for (int mt = 0; mt < 2; ++mt)
#pragma unroll
    for (int dt = 0; dt < 8; ++dt)
#pragma unroll
      for (int r = 0; r < 4; ++r) {
        const int row = qt * 128 + 32 * w + 16 * mt + 4 * quad + r;
        const float v = o[mt][dt][r] / l_run[mt][r];
        Ctx[((size_t)(b * 2048 + row)) * 2048 + h * 128 + 16 * dt + lc] = f2bf(v);
      }
}

// ---------------------------------------------------------------------------
extern "C" void kernel_launch(void* const* d_in, const int* in_sizes, int n_in,
                              void* d_out, int out_size, void* d_ws, size_t ws_size,
                              hipStream_t stream) {
  const float* x  = (const float*)d_in[0];
  const float* Wq = (const float*)d_in[1];
  const float* Wk = (const float*)d_in[2];
  const float* Wv = (const float*)d_in[3];
  const float* Wo = (const float*)d_in[4];
  float* out = (float*)d_out;

  char* ws = (char*)d_ws;
  size_t off = 0;
  auto alloc = [&](size_t bytes) {
    char* p = ws + off;
    off += (bytes + 255) & ~(size_t)255;
    return p;
  };
  const size_t XE = (size_t)4096 * 2048;   // B*S x H elements
  const size_t WE = (size_t)2048 * 2048;

  u16* xh  = (u16*)alloc(XE * 2);
  u16* xl  = (u16*)alloc(XE * 2);
  u16* Wqh = (u16*)alloc(WE * 2);
  u16* Wql = (u16*)alloc(WE * 2);
  u16* Wkh = (u16*)alloc(WE * 2);
  u16* Wkl = (u16*)alloc(WE * 2);
  u16* Wvh = (u16*)alloc(WE * 2);
  u16* Woh = (u16*)alloc(WE * 2);
  u16* Qhb = (u16*)alloc(XE * 2);
  u16* Qlb = (u16*)alloc(XE * 2);
  u16* Khb = (u16*)alloc(XE * 2);
  u16* Klb = (u16*)alloc(XE * 2);
  u16* Vtb = (u16*)alloc(XE * 2);   // V^T: [2048 dims][4096 seq]
  u16* Ctxb = (u16*)alloc(XE * 2);
  float* cosT = (float*)alloc((size_t)2048 * 64 * 4);
  float* sinT = (float*)alloc((size_t)2048 * 64 * 4);
  (void)ws_size;  // requires ~170 MB of workspace
  (void)in_sizes; (void)n_in; (void)out_size;

  // 1) precision split + RoPE tables
  split_bf16<<<8192, 256, 0, stream>>>(x, xh, xl, (int)(XE / 4));
  split_bf16<<<4096, 256, 0, stream>>>(Wq, Wqh, Wql, (int)(WE / 4));
  split_bf16<<<4096, 256, 0, stream>>>(Wk, Wkh, Wkl, (int)(WE / 4));
  split_bf16<<<4096, 256, 0, stream>>>(Wv, Wvh, nullptr, (int)(WE / 4));
  split_bf16<<<4096, 256, 0, stream>>>(Wo, Woh, nullptr, (int)(WE / 4));
  rope_tab<<<512, 256, 0, stream>>>(cosT, sinT);

  // 2) projections: Q,K split-precision with fused RoPE; V^T directly
  gemm_bt<3, 1, 1><<<dim3(16, 32), 256, 0, stream>>>(
      xh, xl, Wqh, Wql, nullptr, Qhb, Qlb, cosT, sinT,
      11.313708498984760f, 4096, 2048, 2048);
  gemm_bt<3, 1, 1><<<dim3(16, 32), 256, 0, stream>>>(
      xh, xl, Wkh, Wkl, nullptr, Khb, Klb, cosT, sinT,
      1.0f, 4096, 2048, 2048);
  // V^T = Wv * x^T :  A=Wv (M=2048 dims), B=x (N=4096 seq)
  gemm_bt<1, 2, 0><<<dim3(32, 16), 256, 0, stream>>>(
      Wvh, nullptr, xh, nullptr, nullptr, Vtb, nullptr, nullptr, nullptr,
      1.0f, 2048, 4096, 2048);

  // 3) causal flash attention
  attn<<<dim3(16, 16, 2), 256, 0, stream>>>(Qhb, Qlb, Khb, Klb, Vtb, Ctxb);

  // 4) output projection -> fp32 d_out
  gemm_bt<1, 0, 0><<<dim3(16, 32), 256, 0, stream>>>(
      Ctxb, nullptr, Woh, nullptr, out, nullptr, nullptr, nullptr, nullptr,
      1.0f, 4096, 2048, 2048);
}